// Round 14
// baseline (964.718 us; speedup 1.0000x reference)
//
#include <hip/hip_runtime.h>

#define NPTS 4096
#define BATCH 4
#define KNN 20
#define ROT 116

__device__ __forceinline__ void vn_lrelu3(float p[3], const float d[3]) {
  float dot = p[0]*d[0] + p[1]*d[1] + p[2]*d[2];
  if (dot < 0.0f) {
    float dsq = d[0]*d[0] + d[1]*d[1] + d[2]*d[2];
    float r = dot / (dsq + 1e-6f);
    p[0] -= r*d[0]; p[1] -= r*d[1]; p[2] -= r*d[2];
  }
}

// Hybrid dual matvec: Wf rows in VGPRs (WF[16] float4), Wd transposed in LDS
// (wdT[i][c], stride 65 -> lane c reads consecutive addresses, conflict-free).
// src = wave's broadcast activation buffer.
__device__ __forceinline__ void matvec_hyb(const float4 WF[16],
                                           const float wdT[][65],
                                           const float src[][4], int c,
                                           float pf[3], float pd[3]) {
  float a0=0,a1=0,a2=0,b0=0,b1=0,b2=0;
#pragma unroll
  for (int i = 0; i < 64; i += 4) {
    const float4 f  = WF[i >> 2];
    const float4 h0 = *(const float4*)src[i+0];
    const float4 h1 = *(const float4*)src[i+1];
    const float4 h2 = *(const float4*)src[i+2];
    const float4 h3 = *(const float4*)src[i+3];
    const float d0 = wdT[i+0][c], d1 = wdT[i+1][c];
    const float d2 = wdT[i+2][c], d3 = wdT[i+3][c];
    a0 += f.x*h0.x + f.y*h1.x + f.z*h2.x + f.w*h3.x;
    a1 += f.x*h0.y + f.y*h1.y + f.z*h2.y + f.w*h3.y;
    a2 += f.x*h0.z + f.y*h1.z + f.z*h2.z + f.w*h3.z;
    b0 += d0*h0.x + d1*h1.x + d2*h2.x + d3*h3.x;
    b1 += d0*h0.y + d1*h1.y + d2*h2.y + d3*h3.y;
    b2 += d0*h0.z + d1*h1.z + d2*h2.z + d3*h3.z;
  }
  pf[0]=a0; pf[1]=a1; pf[2]=a2; pd[0]=b0; pd[1]=b1; pd[2]=b2;
}

template<bool VNT>
__device__ __forceinline__ void load_wf(const float* __restrict__ Wf, int c,
                                        float4 WF[16]) {
#pragma unroll
  for (int i = 0; i < 16; ++i) WF[i] = *(const float4*)(Wf + c * 64 + i * 4);
  if (VNT) {
    float s = 0.f;
#pragma unroll
    for (int i = 0; i < 16; ++i) s += WF[i].x + WF[i].y + WF[i].z + WF[i].w;
    s = 1.0f / s;
#pragma unroll
    for (int i = 0; i < 16; ++i) {
      WF[i].x *= s; WF[i].y *= s; WF[i].z *= s; WF[i].w *= s;
    }
  }
}

// ---------------- K1: KNN via histogram select (unchanged) ----------------
__global__ __launch_bounds__(256) void knn_kernel(const float* __restrict__ x,
                                                  int* __restrict__ knn) {
  const int row = blockIdx.x;
  const int b = row >> 12, i = row & (NPTS - 1);
  const float* __restrict__ xb = x + b * 3 * NPTS;
  const float cx = xb[i], cy = xb[NPTS + i], cz = xb[2 * NPTS + i];
  const int t = threadIdx.x;
  const int j0 = t << 4;

  __shared__ unsigned int hist[2048];
  __shared__ unsigned int ld_[384];
  __shared__ int lj_[384];
  __shared__ unsigned int lcount;
  __shared__ int s_B;
  __shared__ int wtot[4];

  for (int k = t; k < 2048; k += 256) hist[k] = 0u;
  if (t == 0) lcount = 0u;
  __syncthreads();

  unsigned int db[16];
#pragma unroll
  for (int q = 0; q < 4; ++q) {
    const float4 px = *(const float4*)(xb + j0 + 4 * q);
    const float4 py = *(const float4*)(xb + NPTS + j0 + 4 * q);
    const float4 pz = *(const float4*)(xb + 2 * NPTS + j0 + 4 * q);
    float dx, dy, dz, dd;
    dx = px.x - cx; dy = py.x - cy; dz = pz.x - cz;
    dd = dx*dx + dy*dy + dz*dz; db[4*q+0] = __float_as_uint(dd);
    dx = px.y - cx; dy = py.y - cy; dz = pz.y - cz;
    dd = dx*dx + dy*dy + dz*dz; db[4*q+1] = __float_as_uint(dd);
    dx = px.z - cx; dy = py.z - cy; dz = pz.z - cz;
    dd = dx*dx + dy*dy + dz*dz; db[4*q+2] = __float_as_uint(dd);
    dx = px.w - cx; dy = py.w - cy; dz = pz.w - cz;
    dd = dx*dx + dy*dy + dz*dz; db[4*q+3] = __float_as_uint(dd);
  }
#pragma unroll
  for (int s = 0; s < 16; ++s) atomicAdd(&hist[db[s] >> 20], 1u);
  __syncthreads();

  int v = 0;
#pragma unroll
  for (int s = 0; s < 8; ++s) v += (int)hist[t * 8 + s];
  const int myps = v;
  const int lane = t & 63;
#pragma unroll
  for (int off = 1; off < 64; off <<= 1) {
    int n = __shfl_up(v, off);
    if (lane >= off) v += n;
  }
  if (lane == 63) wtot[t >> 6] = v;
  __syncthreads();
  int woff = 0;
#pragma unroll
  for (int w = 0; w < 4; ++w) if (w < (t >> 6)) woff += wtot[w];
  const int cum_in = v + woff;
  const int cum_ex = cum_in - myps;
  if (cum_ex < KNN && cum_in >= KNN) {
    int cum = cum_ex, B = t * 8;
    for (int s = 0; s < 8; ++s) {
      const int hh = (int)hist[t * 8 + s];
      if (cum + hh >= KNN) { B = t * 8 + s; break; }
      cum += hh;
    }
    s_B = B;
  }
  __syncthreads();
  const unsigned int Bb = (unsigned int)s_B;
#pragma unroll
  for (int s = 0; s < 16; ++s) {
    if ((db[s] >> 20) <= Bb) {
      unsigned int pos = atomicAdd(&lcount, 1u);
      if (pos < 384u) { ld_[pos] = db[s]; lj_[pos] = j0 + s; }
    }
  }
  __syncthreads();
  const int n = min((int)lcount, 384);
  for (int idx = t; idx < n; idx += 256) {
    const unsigned int kd = ld_[idx]; const int kj = lj_[idx];
    int rank = 0;
    for (int m = 0; m < n; ++m) {
      const unsigned int md = ld_[m];
      rank += (md < kd || (md == kd && lj_[m] < kj)) ? 1 : 0;
    }
    if (rank < KNN) knn[row * KNN + rank] = kj;
  }
}

// ------- K2: edge features + first VNT layer + mean over k (4 pts/block) -------
__global__ __launch_bounds__(256) void edge_kernel(const float* __restrict__ x,
                                                   const int* __restrict__ knn,
                                                   const float* __restrict__ Wf,
                                                   const float* __restrict__ Wd,
                                                   float* __restrict__ h) {
  const int g = threadIdx.x >> 6;
  const int lane = threadIdx.x & 63;
  const int p = (blockIdx.x << 2) + g;
  const int b = p >> 12, i = p & (NPTS - 1);
  const float* xb = x + b * 3 * NPTS;
  const float cx = xb[i], cy = xb[NPTS + i], cz = xb[2 * NPTS + i];
  __shared__ float e[4][KNN][3][3];
  if (lane < KNN) {
    int j = knn[p * KNN + lane];
    float nx = xb[j], ny = xb[NPTS + j], nz = xb[2 * NPTS + j];
    e[g][lane][0][0] = nx - cx; e[g][lane][0][1] = ny - cy; e[g][lane][0][2] = nz - cz;
    e[g][lane][1][0] = cx;      e[g][lane][1][1] = cy;      e[g][lane][1][2] = cz;
    e[g][lane][2][0] = ny * cz - nz * cy;
    e[g][lane][2][1] = nz * cx - nx * cz;
    e[g][lane][2][2] = nx * cy - ny * cx;
  }
  __syncthreads();
  const int c = lane;
  float f0 = Wf[c * 3 + 0], f1 = Wf[c * 3 + 1], f2 = Wf[c * 3 + 2];
  float s = 1.0f / (f0 + f1 + f2);
  f0 *= s; f1 *= s; f2 *= s;
  const float d0 = Wd[c * 3 + 0], d1 = Wd[c * 3 + 1], d2 = Wd[c * 3 + 2];
  float a0 = 0.f, a1 = 0.f, a2 = 0.f;
  for (int k = 0; k < KNN; ++k) {
    float pv[3], dv[3];
#pragma unroll
    for (int v = 0; v < 3; ++v) {
      pv[v] = f0 * e[g][k][0][v] + f1 * e[g][k][1][v] + f2 * e[g][k][2][v];
      dv[v] = d0 * e[g][k][0][v] + d1 * e[g][k][1][v] + d2 * e[g][k][2][v];
    }
    vn_lrelu3(pv, dv);
    a0 += pv[0]; a1 += pv[1]; a2 += pv[2];
  }
  const float inv = 1.0f / KNN;
  float* hp = h + p * 192 + c * 3;
  hp[0] = a0 * inv; hp[1] = a1 * inv; hp[2] = a2 * inv;
}

// ------- K3: one 64->64 VN(T) layer, hybrid weights. Grid 1024, 4 pts/wave.
//   In-place safe (out == in): hin staged from prefetched regs before store. -------
template<bool VNT>
__global__ __launch_bounds__(256, 3) void layer_hyb(
    const float* __restrict__ in,
    const float* __restrict__ Wf, const float* __restrict__ Wd,
    float* __restrict__ out) {
  __shared__ float wdT[64][65];
  __shared__ float hin[4][64][4];
  const int t = threadIdx.x, q = t >> 6, c = t & 63;
  for (int e = t; e < 4096; e += 256) wdT[e & 63][e >> 6] = Wd[e];
  float4 WF[16];
  load_wf<VNT>(Wf, c, WF);
  __syncthreads();
  const int pbase = (blockIdx.x * 4 + q) * 4;
  const float* ip = in + (size_t)pbase * 192 + c * 3;
  float h0 = ip[0], h1 = ip[1], h2 = ip[2];
  for (int g = 0; g < 4; ++g) {
    hin[q][c][0] = h0; hin[q][c][1] = h1; hin[q][c][2] = h2;
    __builtin_amdgcn_wave_barrier();
    if (g < 3) {
      const float* np = in + (size_t)(pbase + g + 1) * 192 + c * 3;
      h0 = np[0]; h1 = np[1]; h2 = np[2];
    }
    float pf[3], pd[3];
    matvec_hyb(WF, wdT, hin[q], c, pf, pd);
    __builtin_amdgcn_wave_barrier();
    vn_lrelu3(pf, pd);
    float* op = out + (size_t)(pbase + g) * 192 + c * 3;
    op[0] = pf[0]; op[1] = pf[1]; op[2] = pf[2];
  }
}

// ------- K4: Wc2 (VNT, hybrid) -> xc; hc = h - xc -> P; xc -> Q (in place over x2). -------
__global__ __launch_bounds__(256, 3) void cxc_hyb(
    const float* __restrict__ x2, float* __restrict__ h, float* __restrict__ xcout,
    const float* __restrict__ Wf, const float* __restrict__ Wd) {
  __shared__ float wdT[64][65];
  __shared__ float hin[4][64][4];
  const int t = threadIdx.x, q = t >> 6, c = t & 63;
  for (int e = t; e < 4096; e += 256) wdT[e & 63][e >> 6] = Wd[e];
  float4 WF[16];
  load_wf<true>(Wf, c, WF);
  __syncthreads();
  const int pbase = (blockIdx.x * 4 + q) * 4;
  const float* ip = x2 + (size_t)pbase * 192 + c * 3;
  const float* hp0 = h + (size_t)pbase * 192 + c * 3;
  float a0 = ip[0], a1 = ip[1], a2 = ip[2];
  float g0 = hp0[0], g1 = hp0[1], g2 = hp0[2];
  for (int g = 0; g < 4; ++g) {
    const float cg0 = g0, cg1 = g1, cg2 = g2;   // current h BEFORE prefetch
    hin[q][c][0] = a0; hin[q][c][1] = a1; hin[q][c][2] = a2;
    __builtin_amdgcn_wave_barrier();
    if (g < 3) {
      const float* np = x2 + (size_t)(pbase + g + 1) * 192 + c * 3;
      const float* nh = h + (size_t)(pbase + g + 1) * 192 + c * 3;
      a0 = np[0]; a1 = np[1]; a2 = np[2];
      g0 = nh[0]; g1 = nh[1]; g2 = nh[2];
    }
    float qf[3], qd[3];
    matvec_hyb(WF, wdT, hin[q], c, qf, qd);
    __builtin_amdgcn_wave_barrier();
    vn_lrelu3(qf, qd);                          // qf = xc
    float* hcp = h + (size_t)(pbase + g) * 192 + c * 3;
    hcp[0] = cg0 - qf[0]; hcp[1] = cg1 - qf[1]; hcp[2] = cg2 - qf[2];
    float* xp = xcout + (size_t)(pbase + g) * 192 + c * 3;
    xp[0] = qf[0]; xp[1] = qf[1]; xp[2] = qf[2];
  }
}

// ------- K5: trans = Wt (VNT, 12ch) over xc, lane quads (c = l>>2, v = l&3). -------
__global__ __launch_bounds__(256) void trans_kernel(
    const float* __restrict__ xc,
    const float* __restrict__ Wtf, const float* __restrict__ Wtd,
    float* __restrict__ trans_part) {
  __shared__ float wtf[12][65], wtd[12][65];
  __shared__ float xpt[4][64][4];
  __shared__ float tred[4][12][3];
  const int t = threadIdx.x, q = t >> 6, l = t & 63;
  for (int e = t; e < 768; e += 256) {
    wtf[e >> 6][e & 63] = Wtf[e]; wtd[e >> 6][e & 63] = Wtd[e];
  }
  __syncthreads();
  if (t < 12) {
    float s = 0.f;
    for (int i = 0; i < 64; ++i) s += wtf[t][i];
    s = 1.0f / s;
    for (int i = 0; i < 64; ++i) wtf[t][i] *= s;
  }
  __syncthreads();
  const int cch = l >> 2, v = l & 3;            // cch 0..15, v 0..3
  const bool act = (cch < 12) && (v < 3);
  float ta = 0.f;
  const int pbase = (blockIdx.x * 4 + q) * 8;
  for (int g = 0; g < 8; ++g) {
    const float* xp = xc + (size_t)(pbase + g) * 192 + l * 3;
    xpt[q][l][0] = xp[0]; xpt[q][l][1] = xp[1]; xpt[q][l][2] = xp[2];
    __builtin_amdgcn_wave_barrier();
    float pf = 0.f, pd = 0.f;
    if (act) {
      for (int i = 0; i < 64; ++i) {
        const float a = xpt[q][i][v];
        pf += wtf[cch][i] * a;
        pd += wtd[cch][i] * a;
      }
    }
    float pp = pf * pd, dd = pd * pd;           // inactive lanes contribute 0
    pp += __shfl_xor(pp, 1); pp += __shfl_xor(pp, 2);
    dd += __shfl_xor(dd, 1); dd += __shfl_xor(dd, 2);
    if (pp < 0.f) pf -= (pp / (dd + 1e-6f)) * pd;
    ta += pf;
    __builtin_amdgcn_wave_barrier();
  }
  if (act) { tred[q][cch][v] = ta; }
  __syncthreads();
  if (t < 36) {
    const int cc = t / 3, vv = t - cc * 3;
    trans_part[blockIdx.x * 36 + t] =
        tred[0][cc][vv] + tred[1][cc][vv] + tred[2][cc][vv] + tred[3][cc][vv];
  }
}

// ------- K6: W2 (VN, hybrid) -> h2 summed over wave's 4 points -> rot partials. -------
__global__ __launch_bounds__(256, 3) void r2_hyb(
    const float* __restrict__ y1,
    const float* __restrict__ Wf, const float* __restrict__ Wd,
    float* __restrict__ rot_part) {
  __shared__ float wdT[64][65];
  __shared__ float hin[4][64][4];
  const int t = threadIdx.x, q = t >> 6, c = t & 63;
  for (int e = t; e < 4096; e += 256) wdT[e & 63][e >> 6] = Wd[e];
  float4 WF[16];
  load_wf<false>(Wf, c, WF);
  __syncthreads();
  const int pbase = (blockIdx.x * 4 + q) * 4;
  const float* ip = y1 + (size_t)pbase * 192 + c * 3;
  float h0 = ip[0], h1 = ip[1], h2 = ip[2];
  float r0 = 0.f, r1 = 0.f, r2 = 0.f;
  for (int g = 0; g < 4; ++g) {
    hin[q][c][0] = h0; hin[q][c][1] = h1; hin[q][c][2] = h2;
    __builtin_amdgcn_wave_barrier();
    if (g < 3) {
      const float* np = y1 + (size_t)(pbase + g + 1) * 192 + c * 3;
      h0 = np[0]; h1 = np[1]; h2 = np[2];
    }
    float pf[3], pd[3];
    matvec_hyb(WF, wdT, hin[q], c, pf, pd);
    __builtin_amdgcn_wave_barrier();
    vn_lrelu3(pf, pd);
    r0 += pf[0]; r1 += pf[1]; r2 += pf[2];
  }
  *(float4*)hin[q][c] = make_float4(r0, r1, r2, 0.f);
  __syncthreads();
  if (t < 192) {
    const int cc = t / 3, vv = t - cc * 3;
    rot_part[blockIdx.x * 192 + t] =
        hin[0][cc][vv] + hin[1][cc][vv] + hin[2][cc][vv] + hin[3][cc][vv];
  }
}

// ------- K7: reduce partials, W3 @ mean(h2), concat [rot(116), trans(12)] -------
__global__ __launch_bounds__(384) void finalize_kernel(const float* __restrict__ rot_part,
                                                       const float* __restrict__ trans_part,
                                                       const float* __restrict__ W3,
                                                       float* __restrict__ out) {
  const int b = blockIdx.x;   // 0..3: 256 rot-blocks, 128 trans-blocks per batch
  const int t = threadIdx.x;
  __shared__ float hsum[64][3];
  if (t < 192) {
    float s = 0.f;
    for (int blk = 0; blk < 256; ++blk)
      s += rot_part[(b * 256 + blk) * 192 + t];
    hsum[t / 3][t % 3] = s * (1.0f / NPTS);
  } else if (t < 228) {
    const int tt = t - 192;
    float s = 0.f;
    for (int blk = 0; blk < 128; ++blk)
      s += trans_part[(b * 128 + blk) * 36 + tt];
    out[b * 384 + 348 + tt] = s * (1.0f / NPTS);
  }
  __syncthreads();
  if (t < 348) {
    const int ch = t / 3, v = t - ch * 3;
    float s = 0.f;
    for (int i = 0; i < 64; ++i) s += W3[ch * 64 + i] * hsum[i][v];
    out[b * 384 + t] = s;
  }
}

extern "C" void kernel_launch(void* const* d_in, const int* in_sizes, int n_in,
                              void* d_out, int out_size, void* d_ws, size_t ws_size,
                              hipStream_t stream) {
  (void)in_sizes; (void)n_in; (void)out_size; (void)ws_size;
  const float* x     = (const float*)d_in[0];
  const float* Wposf = (const float*)d_in[1];
  const float* Wposd = (const float*)d_in[2];
  const float* Wc1f  = (const float*)d_in[3];
  const float* Wc1d  = (const float*)d_in[4];
  const float* Wc2f  = (const float*)d_in[5];
  const float* Wc2d  = (const float*)d_in[6];
  const float* Wtf   = (const float*)d_in[7];
  const float* Wtd   = (const float*)d_in[8];
  const float* W1f   = (const float*)d_in[9];
  const float* W1d   = (const float*)d_in[10];
  const float* W2f   = (const float*)d_in[11];
  const float* W2d   = (const float*)d_in[12];
  const float* W3    = (const float*)d_in[13];
  float* out = (float*)d_out;

  char* ws = (char*)d_ws;
  int*   knn        = (int*)ws;                          // 1,310,720 B
  float* P          = (float*)(ws + 1310720);            // h -> hc -> y1 (in place)
  float* Q          = (float*)(ws + 13893632);           // x2 -> xc (in place)
  float* trans_part = (float*)(ws + 26476544);           // 512*36*4  = 73,728 B
  float* rot_part   = (float*)(ws + 26550272);           // 1024*192*4 = 786,432 B

  knn_kernel<<<BATCH * NPTS, 256, 0, stream>>>(x, knn);
  edge_kernel<<<BATCH * NPTS / 4, 256, 0, stream>>>(x, knn, Wposf, Wposd, P);
  layer_hyb<true><<<1024, 256, 0, stream>>>(P, Wc1f, Wc1d, Q);       // h -> x2
  cxc_hyb<<<1024, 256, 0, stream>>>(Q, P, Q, Wc2f, Wc2d);            // x2 -> xc; P := h - xc
  trans_kernel<<<512, 256, 0, stream>>>(Q, Wtf, Wtd, trans_part);    // xc -> trans partials
  layer_hyb<false><<<1024, 256, 0, stream>>>(P, W1f, W1d, P);        // hc -> y1 (in place)
  r2_hyb<<<1024, 256, 0, stream>>>(P, W2f, W2d, rot_part);           // y1 -> rot partials
  finalize_kernel<<<BATCH, 384, 0, stream>>>(rot_part, trans_part, W3, out);
}

// Round 15
// 312.280 us; speedup vs baseline: 3.0893x; 3.0893x over previous
//
#include <hip/hip_runtime.h>

#define NPTS 4096
#define BATCH 4
#define KNN 20
#define ROT 116

__device__ __forceinline__ void vn_lrelu3(float p[3], const float d[3]) {
  float dot = p[0]*d[0] + p[1]*d[1] + p[2]*d[2];
  if (dot < 0.0f) {
    float dsq = d[0]*d[0] + d[1]*d[1] + d[2]*d[2];
    float r = dot / (dsq + 1e-6f);
    p[0] -= r*d[0]; p[1] -= r*d[1]; p[2] -= r*d[2];
  }
}

// Hybrid dual matvec: Wf rows in VGPRs (WF[16] float4), Wd transposed in LDS
// (wdT[i][c], stride 65 -> lane c reads consecutive addresses, conflict-free).
// src = wave's broadcast activation buffer (same-address float4 = broadcast).
__device__ __forceinline__ void matvec_hyb(const float4 WF[16],
                                           const float wdT[][65],
                                           const float src[][4], int c,
                                           float pf[3], float pd[3]) {
  float a0=0,a1=0,a2=0,b0=0,b1=0,b2=0;
#pragma unroll
  for (int i = 0; i < 64; i += 4) {
    const float4 f  = WF[i >> 2];
    const float4 h0 = *(const float4*)src[i+0];
    const float4 h1 = *(const float4*)src[i+1];
    const float4 h2 = *(const float4*)src[i+2];
    const float4 h3 = *(const float4*)src[i+3];
    const float d0 = wdT[i+0][c], d1 = wdT[i+1][c];
    const float d2 = wdT[i+2][c], d3 = wdT[i+3][c];
    a0 += f.x*h0.x + f.y*h1.x + f.z*h2.x + f.w*h3.x;
    a1 += f.x*h0.y + f.y*h1.y + f.z*h2.y + f.w*h3.y;
    a2 += f.x*h0.z + f.y*h1.z + f.z*h2.z + f.w*h3.z;
    b0 += d0*h0.x + d1*h1.x + d2*h2.x + d3*h3.x;
    b1 += d0*h0.y + d1*h1.y + d2*h2.y + d3*h3.y;
    b2 += d0*h0.z + d1*h1.z + d2*h2.z + d3*h3.z;
  }
  pf[0]=a0; pf[1]=a1; pf[2]=a2; pd[0]=b0; pd[1]=b1; pd[2]=b2;
}

template<bool VNT>
__device__ __forceinline__ void load_wf(const float* __restrict__ Wf, int c,
                                        float4 WF[16]) {
#pragma unroll
  for (int i = 0; i < 16; ++i) WF[i] = *(const float4*)(Wf + c * 64 + i * 4);
  if (VNT) {
    float s = 0.f;
#pragma unroll
    for (int i = 0; i < 16; ++i) s += WF[i].x + WF[i].y + WF[i].z + WF[i].w;
    s = 1.0f / s;
#pragma unroll
    for (int i = 0; i < 16; ++i) {
      WF[i].x *= s; WF[i].y *= s; WF[i].z *= s; WF[i].w *= s;
    }
  }
}

// ---------------- K1: KNN via histogram select (unchanged) ----------------
__global__ __launch_bounds__(256) void knn_kernel(const float* __restrict__ x,
                                                  int* __restrict__ knn) {
  const int row = blockIdx.x;
  const int b = row >> 12, i = row & (NPTS - 1);
  const float* __restrict__ xb = x + b * 3 * NPTS;
  const float cx = xb[i], cy = xb[NPTS + i], cz = xb[2 * NPTS + i];
  const int t = threadIdx.x;
  const int j0 = t << 4;

  __shared__ unsigned int hist[2048];
  __shared__ unsigned int ld_[384];
  __shared__ int lj_[384];
  __shared__ unsigned int lcount;
  __shared__ int s_B;
  __shared__ int wtot[4];

  for (int k = t; k < 2048; k += 256) hist[k] = 0u;
  if (t == 0) lcount = 0u;
  __syncthreads();

  unsigned int db[16];
#pragma unroll
  for (int q = 0; q < 4; ++q) {
    const float4 px = *(const float4*)(xb + j0 + 4 * q);
    const float4 py = *(const float4*)(xb + NPTS + j0 + 4 * q);
    const float4 pz = *(const float4*)(xb + 2 * NPTS + j0 + 4 * q);
    float dx, dy, dz, dd;
    dx = px.x - cx; dy = py.x - cy; dz = pz.x - cz;
    dd = dx*dx + dy*dy + dz*dz; db[4*q+0] = __float_as_uint(dd);
    dx = px.y - cx; dy = py.y - cy; dz = pz.y - cz;
    dd = dx*dx + dy*dy + dz*dz; db[4*q+1] = __float_as_uint(dd);
    dx = px.z - cx; dy = py.z - cy; dz = pz.z - cz;
    dd = dx*dx + dy*dy + dz*dz; db[4*q+2] = __float_as_uint(dd);
    dx = px.w - cx; dy = py.w - cy; dz = pz.w - cz;
    dd = dx*dx + dy*dy + dz*dz; db[4*q+3] = __float_as_uint(dd);
  }
#pragma unroll
  for (int s = 0; s < 16; ++s) atomicAdd(&hist[db[s] >> 20], 1u);
  __syncthreads();

  int v = 0;
#pragma unroll
  for (int s = 0; s < 8; ++s) v += (int)hist[t * 8 + s];
  const int myps = v;
  const int lane = t & 63;
#pragma unroll
  for (int off = 1; off < 64; off <<= 1) {
    int n = __shfl_up(v, off);
    if (lane >= off) v += n;
  }
  if (lane == 63) wtot[t >> 6] = v;
  __syncthreads();
  int woff = 0;
#pragma unroll
  for (int w = 0; w < 4; ++w) if (w < (t >> 6)) woff += wtot[w];
  const int cum_in = v + woff;
  const int cum_ex = cum_in - myps;
  if (cum_ex < KNN && cum_in >= KNN) {
    int cum = cum_ex, B = t * 8;
    for (int s = 0; s < 8; ++s) {
      const int hh = (int)hist[t * 8 + s];
      if (cum + hh >= KNN) { B = t * 8 + s; break; }
      cum += hh;
    }
    s_B = B;
  }
  __syncthreads();
  const unsigned int Bb = (unsigned int)s_B;
#pragma unroll
  for (int s = 0; s < 16; ++s) {
    if ((db[s] >> 20) <= Bb) {
      unsigned int pos = atomicAdd(&lcount, 1u);
      if (pos < 384u) { ld_[pos] = db[s]; lj_[pos] = j0 + s; }
    }
  }
  __syncthreads();
  const int n = min((int)lcount, 384);
  for (int idx = t; idx < n; idx += 256) {
    const unsigned int kd = ld_[idx]; const int kj = lj_[idx];
    int rank = 0;
    for (int m = 0; m < n; ++m) {
      const unsigned int md = ld_[m];
      rank += (md < kd || (md == kd && lj_[m] < kj)) ? 1 : 0;
    }
    if (rank < KNN) knn[row * KNN + rank] = kj;
  }
}

// ------- K2: edge features + first VNT layer + mean over k (4 pts/block) -------
__global__ __launch_bounds__(256) void edge_kernel(const float* __restrict__ x,
                                                   const int* __restrict__ knn,
                                                   const float* __restrict__ Wf,
                                                   const float* __restrict__ Wd,
                                                   float* __restrict__ h) {
  const int g = threadIdx.x >> 6;
  const int lane = threadIdx.x & 63;
  const int p = (blockIdx.x << 2) + g;
  const int b = p >> 12, i = p & (NPTS - 1);
  const float* xb = x + b * 3 * NPTS;
  const float cx = xb[i], cy = xb[NPTS + i], cz = xb[2 * NPTS + i];
  __shared__ float e[4][KNN][3][3];
  if (lane < KNN) {
    int j = knn[p * KNN + lane];
    float nx = xb[j], ny = xb[NPTS + j], nz = xb[2 * NPTS + j];
    e[g][lane][0][0] = nx - cx; e[g][lane][0][1] = ny - cy; e[g][lane][0][2] = nz - cz;
    e[g][lane][1][0] = cx;      e[g][lane][1][1] = cy;      e[g][lane][1][2] = cz;
    e[g][lane][2][0] = ny * cz - nz * cy;
    e[g][lane][2][1] = nz * cx - nx * cz;
    e[g][lane][2][2] = nx * cy - ny * cx;
  }
  __syncthreads();
  const int c = lane;
  float f0 = Wf[c * 3 + 0], f1 = Wf[c * 3 + 1], f2 = Wf[c * 3 + 2];
  float s = 1.0f / (f0 + f1 + f2);
  f0 *= s; f1 *= s; f2 *= s;
  const float d0 = Wd[c * 3 + 0], d1 = Wd[c * 3 + 1], d2 = Wd[c * 3 + 2];
  float a0 = 0.f, a1 = 0.f, a2 = 0.f;
  for (int k = 0; k < KNN; ++k) {
    float pv[3], dv[3];
#pragma unroll
    for (int v = 0; v < 3; ++v) {
      pv[v] = f0 * e[g][k][0][v] + f1 * e[g][k][1][v] + f2 * e[g][k][2][v];
      dv[v] = d0 * e[g][k][0][v] + d1 * e[g][k][1][v] + d2 * e[g][k][2][v];
    }
    vn_lrelu3(pv, dv);
    a0 += pv[0]; a1 += pv[1]; a2 += pv[2];
  }
  const float inv = 1.0f / KNN;
  float* hp = h + p * 192 + c * 3;
  hp[0] = a0 * inv; hp[1] = a1 * inv; hp[2] = a2 * inv;
}

// ------- K3: one 64->64 VN(T) layer, hybrid weights. Grid 512, 8 pts/wave.
//   NO min-waves cap (round-14 lesson: the cap forced WF to scratch).
//   In-place safe (out == in): wave's own points only. -------
template<bool VNT>
__global__ __launch_bounds__(256) void layer_hyb(
    const float* __restrict__ in,
    const float* __restrict__ Wf, const float* __restrict__ Wd,
    float* __restrict__ out) {
  __shared__ float wdT[64][65];
  __shared__ float hin[4][64][4];
  const int t = threadIdx.x, q = t >> 6, c = t & 63;
  for (int e = t; e < 4096; e += 256) wdT[e & 63][e >> 6] = Wd[e];
  float4 WF[16];
  load_wf<VNT>(Wf, c, WF);
  __syncthreads();
  const int pbase = (blockIdx.x * 4 + q) * 8;
  const float* ip = in + (size_t)pbase * 192 + c * 3;
  float h0 = ip[0], h1 = ip[1], h2 = ip[2];
  for (int g = 0; g < 8; ++g) {
    hin[q][c][0] = h0; hin[q][c][1] = h1; hin[q][c][2] = h2;
    __builtin_amdgcn_wave_barrier();
    if (g < 7) {                       // prefetch next point under the FMAs
      const float* np = in + (size_t)(pbase + g + 1) * 192 + c * 3;
      h0 = np[0]; h1 = np[1]; h2 = np[2];
    }
    float pf[3], pd[3];
    matvec_hyb(WF, wdT, hin[q], c, pf, pd);
    __builtin_amdgcn_wave_barrier();
    vn_lrelu3(pf, pd);
    float* op = out + (size_t)(pbase + g) * 192 + c * 3;
    op[0] = pf[0]; op[1] = pf[1]; op[2] = pf[2];
  }
}

// ------- K4: Wc2 (VNT, hybrid) -> xc; hc = h - xc -> P; xc -> Q (in place). -------
__global__ __launch_bounds__(256) void cxc_hyb(
    const float* __restrict__ x2, float* __restrict__ h, float* __restrict__ xcout,
    const float* __restrict__ Wf, const float* __restrict__ Wd) {
  __shared__ float wdT[64][65];
  __shared__ float hin[4][64][4];
  const int t = threadIdx.x, q = t >> 6, c = t & 63;
  for (int e = t; e < 4096; e += 256) wdT[e & 63][e >> 6] = Wd[e];
  float4 WF[16];
  load_wf<true>(Wf, c, WF);
  __syncthreads();
  const int pbase = (blockIdx.x * 4 + q) * 8;
  const float* ip = x2 + (size_t)pbase * 192 + c * 3;
  const float* hp0 = h + (size_t)pbase * 192 + c * 3;
  float a0 = ip[0], a1 = ip[1], a2 = ip[2];
  float g0 = hp0[0], g1 = hp0[1], g2 = hp0[2];
  for (int g = 0; g < 8; ++g) {
    const float cg0 = g0, cg1 = g1, cg2 = g2;   // current h BEFORE prefetch
    hin[q][c][0] = a0; hin[q][c][1] = a1; hin[q][c][2] = a2;
    __builtin_amdgcn_wave_barrier();
    if (g < 7) {
      const float* np = x2 + (size_t)(pbase + g + 1) * 192 + c * 3;
      const float* nh = h + (size_t)(pbase + g + 1) * 192 + c * 3;
      a0 = np[0]; a1 = np[1]; a2 = np[2];
      g0 = nh[0]; g1 = nh[1]; g2 = nh[2];
    }
    float qf[3], qd[3];
    matvec_hyb(WF, wdT, hin[q], c, qf, qd);
    __builtin_amdgcn_wave_barrier();
    vn_lrelu3(qf, qd);                          // qf = xc
    float* hcp = h + (size_t)(pbase + g) * 192 + c * 3;
    hcp[0] = cg0 - qf[0]; hcp[1] = cg1 - qf[1]; hcp[2] = cg2 - qf[2];
    float* xp = xcout + (size_t)(pbase + g) * 192 + c * 3;
    xp[0] = qf[0]; xp[1] = qf[1]; xp[2] = qf[2];
  }
}

// ------- K5: trans = Wt (VNT, 12ch) over xc, lane quads (c = l>>2, v = l&3). -------
__global__ __launch_bounds__(256) void trans_kernel(
    const float* __restrict__ xc,
    const float* __restrict__ Wtf, const float* __restrict__ Wtd,
    float* __restrict__ trans_part) {
  __shared__ float wtf[12][65], wtd[12][65];
  __shared__ float xpt[4][64][4];
  __shared__ float tred[4][12][3];
  const int t = threadIdx.x, q = t >> 6, l = t & 63;
  for (int e = t; e < 768; e += 256) {
    wtf[e >> 6][e & 63] = Wtf[e]; wtd[e >> 6][e & 63] = Wtd[e];
  }
  __syncthreads();
  if (t < 12) {
    float s = 0.f;
    for (int i = 0; i < 64; ++i) s += wtf[t][i];
    s = 1.0f / s;
    for (int i = 0; i < 64; ++i) wtf[t][i] *= s;
  }
  __syncthreads();
  const int cch = l >> 2, v = l & 3;            // cch 0..15, v 0..3
  const bool act = (cch < 12) && (v < 3);
  float ta = 0.f;
  const int pbase = (blockIdx.x * 4 + q) * 8;
  for (int g = 0; g < 8; ++g) {
    const float* xp = xc + (size_t)(pbase + g) * 192 + l * 3;
    xpt[q][l][0] = xp[0]; xpt[q][l][1] = xp[1]; xpt[q][l][2] = xp[2];
    __builtin_amdgcn_wave_barrier();
    float pf = 0.f, pd = 0.f;
    if (act) {
      for (int i = 0; i < 64; ++i) {
        const float a = xpt[q][i][v];
        pf += wtf[cch][i] * a;
        pd += wtd[cch][i] * a;
      }
    }
    float pp = pf * pd, dd = pd * pd;           // inactive lanes contribute 0
    pp += __shfl_xor(pp, 1); pp += __shfl_xor(pp, 2);
    dd += __shfl_xor(dd, 1); dd += __shfl_xor(dd, 2);
    if (pp < 0.f) pf -= (pp / (dd + 1e-6f)) * pd;
    ta += pf;
    __builtin_amdgcn_wave_barrier();
  }
  if (act) { tred[q][cch][v] = ta; }
  __syncthreads();
  if (t < 36) {
    const int cc = t / 3, vv = t - cc * 3;
    trans_part[blockIdx.x * 36 + t] =
        tred[0][cc][vv] + tred[1][cc][vv] + tred[2][cc][vv] + tred[3][cc][vv];
  }
}

// ------- K6: W2 (VN, hybrid) -> h2 summed over wave's 8 points -> rot partials. -------
__global__ __launch_bounds__(256) void r2_hyb(
    const float* __restrict__ y1,
    const float* __restrict__ Wf, const float* __restrict__ Wd,
    float* __restrict__ rot_part) {
  __shared__ float wdT[64][65];
  __shared__ float hin[4][64][4];
  const int t = threadIdx.x, q = t >> 6, c = t & 63;
  for (int e = t; e < 4096; e += 256) wdT[e & 63][e >> 6] = Wd[e];
  float4 WF[16];
  load_wf<false>(Wf, c, WF);
  __syncthreads();
  const int pbase = (blockIdx.x * 4 + q) * 8;
  const float* ip = y1 + (size_t)pbase * 192 + c * 3;
  float h0 = ip[0], h1 = ip[1], h2 = ip[2];
  float r0 = 0.f, r1 = 0.f, r2 = 0.f;
  for (int g = 0; g < 8; ++g) {
    hin[q][c][0] = h0; hin[q][c][1] = h1; hin[q][c][2] = h2;
    __builtin_amdgcn_wave_barrier();
    if (g < 7) {
      const float* np = y1 + (size_t)(pbase + g + 1) * 192 + c * 3;
      h0 = np[0]; h1 = np[1]; h2 = np[2];
    }
    float pf[3], pd[3];
    matvec_hyb(WF, wdT, hin[q], c, pf, pd);
    __builtin_amdgcn_wave_barrier();
    vn_lrelu3(pf, pd);
    r0 += pf[0]; r1 += pf[1]; r2 += pf[2];
  }
  *(float4*)hin[q][c] = make_float4(r0, r1, r2, 0.f);
  __syncthreads();
  if (t < 192) {
    const int cc = t / 3, vv = t - cc * 3;
    rot_part[blockIdx.x * 192 + t] =
        hin[0][cc][vv] + hin[1][cc][vv] + hin[2][cc][vv] + hin[3][cc][vv];
  }
}

// ------- K7: reduce partials, W3 @ mean(h2), concat [rot(116), trans(12)] -------
__global__ __launch_bounds__(384) void finalize_kernel(const float* __restrict__ rot_part,
                                                       const float* __restrict__ trans_part,
                                                       const float* __restrict__ W3,
                                                       float* __restrict__ out) {
  const int b = blockIdx.x;   // 0..3 (128 blocks per batch at grid 512)
  const int t = threadIdx.x;
  __shared__ float hsum[64][3];
  if (t < 192) {
    float s = 0.f;
    for (int blk = 0; blk < 128; ++blk)
      s += rot_part[(b * 128 + blk) * 192 + t];
    hsum[t / 3][t % 3] = s * (1.0f / NPTS);
  } else if (t < 228) {
    const int tt = t - 192;
    float s = 0.f;
    for (int blk = 0; blk < 128; ++blk)
      s += trans_part[(b * 128 + blk) * 36 + tt];
    out[b * 384 + 348 + tt] = s * (1.0f / NPTS);
  }
  __syncthreads();
  if (t < 348) {
    const int ch = t / 3, v = t - ch * 3;
    float s = 0.f;
    for (int i = 0; i < 64; ++i) s += W3[ch * 64 + i] * hsum[i][v];
    out[b * 384 + t] = s;
  }
}

extern "C" void kernel_launch(void* const* d_in, const int* in_sizes, int n_in,
                              void* d_out, int out_size, void* d_ws, size_t ws_size,
                              hipStream_t stream) {
  (void)in_sizes; (void)n_in; (void)out_size; (void)ws_size;
  const float* x     = (const float*)d_in[0];
  const float* Wposf = (const float*)d_in[1];
  const float* Wposd = (const float*)d_in[2];
  const float* Wc1f  = (const float*)d_in[3];
  const float* Wc1d  = (const float*)d_in[4];
  const float* Wc2f  = (const float*)d_in[5];
  const float* Wc2d  = (const float*)d_in[6];
  const float* Wtf   = (const float*)d_in[7];
  const float* Wtd   = (const float*)d_in[8];
  const float* W1f   = (const float*)d_in[9];
  const float* W1d   = (const float*)d_in[10];
  const float* W2f   = (const float*)d_in[11];
  const float* W2d   = (const float*)d_in[12];
  const float* W3    = (const float*)d_in[13];
  float* out = (float*)d_out;

  char* ws = (char*)d_ws;
  int*   knn        = (int*)ws;                          // 1,310,720 B
  float* P          = (float*)(ws + 1310720);            // h -> hc -> y1 (in place)
  float* Q          = (float*)(ws + 13893632);           // x2 -> xc (in place)
  float* trans_part = (float*)(ws + 26476544);           // 512*36*4  = 73,728 B
  float* rot_part   = (float*)(ws + 26550272);           // 512*192*4 = 393,216 B

  knn_kernel<<<BATCH * NPTS, 256, 0, stream>>>(x, knn);
  edge_kernel<<<BATCH * NPTS / 4, 256, 0, stream>>>(x, knn, Wposf, Wposd, P);
  layer_hyb<true><<<512, 256, 0, stream>>>(P, Wc1f, Wc1d, Q);        // h -> x2
  cxc_hyb<<<512, 256, 0, stream>>>(Q, P, Q, Wc2f, Wc2d);             // x2 -> xc; P := h - xc
  trans_kernel<<<512, 256, 0, stream>>>(Q, Wtf, Wtd, trans_part);    // xc -> trans partials
  layer_hyb<false><<<512, 256, 0, stream>>>(P, W1f, W1d, P);         // hc -> y1 (in place)
  r2_hyb<<<512, 256, 0, stream>>>(P, W2f, W2d, rot_part);            // y1 -> rot partials
  finalize_kernel<<<BATCH, 384, 0, stream>>>(rot_part, trans_part, W3, out);
}

// Round 16
// 213.707 us; speedup vs baseline: 4.5142x; 1.4612x over previous
//
#include <hip/hip_runtime.h>

#define NPTS 4096
#define BATCH 4
#define KNN 20
#define ROT 116

__device__ __forceinline__ void vn_lrelu3(float p[3], const float d[3]) {
  float dot = p[0]*d[0] + p[1]*d[1] + p[2]*d[2];
  if (dot < 0.0f) {
    float dsq = d[0]*d[0] + d[1]*d[1] + d[2]*d[2];
    float r = dot / (dsq + 1e-6f);
    p[0] -= r*d[0]; p[1] -= r*d[1]; p[2] -= r*d[2];
  }
}

// ---------------- K1: KNN via histogram select (unchanged) ----------------
__global__ __launch_bounds__(256) void knn_kernel(const float* __restrict__ x,
                                                  int* __restrict__ knn) {
  const int row = blockIdx.x;
  const int b = row >> 12, i = row & (NPTS - 1);
  const float* __restrict__ xb = x + b * 3 * NPTS;
  const float cx = xb[i], cy = xb[NPTS + i], cz = xb[2 * NPTS + i];
  const int t = threadIdx.x;
  const int j0 = t << 4;

  __shared__ unsigned int hist[2048];
  __shared__ unsigned int ld_[384];
  __shared__ int lj_[384];
  __shared__ unsigned int lcount;
  __shared__ int s_B;
  __shared__ int wtot[4];

  for (int k = t; k < 2048; k += 256) hist[k] = 0u;
  if (t == 0) lcount = 0u;
  __syncthreads();

  unsigned int db[16];
#pragma unroll
  for (int q = 0; q < 4; ++q) {
    const float4 px = *(const float4*)(xb + j0 + 4 * q);
    const float4 py = *(const float4*)(xb + NPTS + j0 + 4 * q);
    const float4 pz = *(const float4*)(xb + 2 * NPTS + j0 + 4 * q);
    float dx, dy, dz, dd;
    dx = px.x - cx; dy = py.x - cy; dz = pz.x - cz;
    dd = dx*dx + dy*dy + dz*dz; db[4*q+0] = __float_as_uint(dd);
    dx = px.y - cx; dy = py.y - cy; dz = pz.y - cz;
    dd = dx*dx + dy*dy + dz*dz; db[4*q+1] = __float_as_uint(dd);
    dx = px.z - cx; dy = py.z - cy; dz = pz.z - cz;
    dd = dx*dx + dy*dy + dz*dz; db[4*q+2] = __float_as_uint(dd);
    dx = px.w - cx; dy = py.w - cy; dz = pz.w - cz;
    dd = dx*dx + dy*dy + dz*dz; db[4*q+3] = __float_as_uint(dd);
  }
#pragma unroll
  for (int s = 0; s < 16; ++s) atomicAdd(&hist[db[s] >> 20], 1u);
  __syncthreads();

  int v = 0;
#pragma unroll
  for (int s = 0; s < 8; ++s) v += (int)hist[t * 8 + s];
  const int myps = v;
  const int lane = t & 63;
#pragma unroll
  for (int off = 1; off < 64; off <<= 1) {
    int n = __shfl_up(v, off);
    if (lane >= off) v += n;
  }
  if (lane == 63) wtot[t >> 6] = v;
  __syncthreads();
  int woff = 0;
#pragma unroll
  for (int w = 0; w < 4; ++w) if (w < (t >> 6)) woff += wtot[w];
  const int cum_in = v + woff;
  const int cum_ex = cum_in - myps;
  if (cum_ex < KNN && cum_in >= KNN) {
    int cum = cum_ex, B = t * 8;
    for (int s = 0; s < 8; ++s) {
      const int hh = (int)hist[t * 8 + s];
      if (cum + hh >= KNN) { B = t * 8 + s; break; }
      cum += hh;
    }
    s_B = B;
  }
  __syncthreads();
  const unsigned int Bb = (unsigned int)s_B;
#pragma unroll
  for (int s = 0; s < 16; ++s) {
    if ((db[s] >> 20) <= Bb) {
      unsigned int pos = atomicAdd(&lcount, 1u);
      if (pos < 384u) { ld_[pos] = db[s]; lj_[pos] = j0 + s; }
    }
  }
  __syncthreads();
  const int n = min((int)lcount, 384);
  for (int idx = t; idx < n; idx += 256) {
    const unsigned int kd = ld_[idx]; const int kj = lj_[idx];
    int rank = 0;
    for (int m = 0; m < n; ++m) {
      const unsigned int md = ld_[m];
      rank += (md < kd || (md == kd && lj_[m] < kj)) ? 1 : 0;
    }
    if (rank < KNN) knn[row * KNN + rank] = kj;
  }
}

// ------- K2: edge features + first VNT layer + mean over k (4 pts/block) -------
__global__ __launch_bounds__(256) void edge_kernel(const float* __restrict__ x,
                                                   const int* __restrict__ knn,
                                                   const float* __restrict__ Wf,
                                                   const float* __restrict__ Wd,
                                                   float* __restrict__ h) {
  const int g = threadIdx.x >> 6;
  const int lane = threadIdx.x & 63;
  const int p = (blockIdx.x << 2) + g;
  const int b = p >> 12, i = p & (NPTS - 1);
  const float* xb = x + b * 3 * NPTS;
  const float cx = xb[i], cy = xb[NPTS + i], cz = xb[2 * NPTS + i];
  __shared__ float e[4][KNN][3][3];
  if (lane < KNN) {
    int j = knn[p * KNN + lane];
    float nx = xb[j], ny = xb[NPTS + j], nz = xb[2 * NPTS + j];
    e[g][lane][0][0] = nx - cx; e[g][lane][0][1] = ny - cy; e[g][lane][0][2] = nz - cz;
    e[g][lane][1][0] = cx;      e[g][lane][1][1] = cy;      e[g][lane][1][2] = cz;
    e[g][lane][2][0] = ny * cz - nz * cy;
    e[g][lane][2][1] = nz * cx - nx * cz;
    e[g][lane][2][2] = nx * cy - ny * cx;
  }
  __syncthreads();
  const int c = lane;
  float f0 = Wf[c * 3 + 0], f1 = Wf[c * 3 + 1], f2 = Wf[c * 3 + 2];
  float s = 1.0f / (f0 + f1 + f2);
  f0 *= s; f1 *= s; f2 *= s;
  const float d0 = Wd[c * 3 + 0], d1 = Wd[c * 3 + 1], d2 = Wd[c * 3 + 2];
  float a0 = 0.f, a1 = 0.f, a2 = 0.f;
  for (int k = 0; k < KNN; ++k) {
    float pv[3], dv[3];
#pragma unroll
    for (int v = 0; v < 3; ++v) {
      pv[v] = f0 * e[g][k][0][v] + f1 * e[g][k][1][v] + f2 * e[g][k][2][v];
      dv[v] = d0 * e[g][k][0][v] + d1 * e[g][k][1][v] + d2 * e[g][k][2][v];
    }
    vn_lrelu3(pv, dv);
    a0 += pv[0]; a1 += pv[1]; a2 += pv[2];
  }
  const float inv = 1.0f / KNN;
  float* hp = h + p * 192 + c * 3;
  hp[0] = a0 * inv; hp[1] = a1 * inv; hp[2] = a2 * inv;
}

// ------- K3: batched 64->64 VN(T) layer. Both weights transposed in LDS
//   (stride 65, lane-consecutive b32 = conflict-free). Wave = 8 points in
//   2 passes of 4; weight reads amortized over 4 points; acc static-indexed.
//   MODE 0: out = lrelu(layer(in)).
//   MODE 1 (cxc): out = xc; aux := aux - xc (hc, read-before-write).
//   MODE 2 (r2): out = rot_part (block reduction of sum over points).
//   In-place safe (out==in): each wave stages its own points before writing. -------
template<bool VNT, int MODE>
__global__ __launch_bounds__(256) void layer_batch(
    const float* in, float* out, float* aux,
    const float* __restrict__ Wf, const float* __restrict__ Wd) {
  __shared__ float wfT[64][65], wdT[64][65];
  __shared__ float act[4][4][64][4];
  const int t = threadIdx.x, q = t >> 6, c = t & 63;
  for (int e = t; e < 4096; e += 256) {
    wfT[e & 63][e >> 6] = Wf[e];
    wdT[e & 63][e >> 6] = Wd[e];
  }
  __syncthreads();
  if (VNT) {
    if (t < 64) {
      float s = 0.f;
      for (int i = 0; i < 64; ++i) s += wfT[i][t];
      s = 1.0f / s;
      for (int i = 0; i < 64; ++i) wfT[i][t] *= s;
    }
    __syncthreads();
  }
  const int pbase = (blockIdx.x * 4 + q) * 8;
  float r0 = 0.f, r1 = 0.f, r2 = 0.f;           // MODE 2 accumulator
  for (int pass = 0; pass < 2; ++pass) {
    const int p0 = pbase + pass * 4;
    // stage this wave's 4 points (b128 writes)
#pragma unroll
    for (int p = 0; p < 4; ++p) {
      const float* ip = in + (size_t)(p0 + p) * 192 + c * 3;
      *(float4*)act[q][p][c] = make_float4(ip[0], ip[1], ip[2], 0.f);
    }
    __builtin_amdgcn_wave_barrier();
    float af[12], ad[12];
#pragma unroll
    for (int e = 0; e < 12; ++e) { af[e] = 0.f; ad[e] = 0.f; }
    for (int i = 0; i < 64; ++i) {
      const float wfv = wfT[i][c];
      const float wdv = wdT[i][c];
#pragma unroll
      for (int p = 0; p < 4; ++p) {
        const float4 hv = *(const float4*)act[q][p][i];   // broadcast
        af[p*3+0] += wfv * hv.x; af[p*3+1] += wfv * hv.y; af[p*3+2] += wfv * hv.z;
        ad[p*3+0] += wdv * hv.x; ad[p*3+1] += wdv * hv.y; ad[p*3+2] += wdv * hv.z;
      }
    }
    __builtin_amdgcn_wave_barrier();
#pragma unroll
    for (int p = 0; p < 4; ++p) {
      float pf[3] = { af[p*3+0], af[p*3+1], af[p*3+2] };
      float pd[3] = { ad[p*3+0], ad[p*3+1], ad[p*3+2] };
      vn_lrelu3(pf, pd);
      const size_t ofs = (size_t)(p0 + p) * 192 + c * 3;
      if (MODE == 0) {
        out[ofs+0] = pf[0]; out[ofs+1] = pf[1]; out[ofs+2] = pf[2];
      } else if (MODE == 1) {
        // hc = h - xc (read aux before overwrite), xc -> out
        const float h0 = aux[ofs+0], h1 = aux[ofs+1], h2 = aux[ofs+2];
        aux[ofs+0] = h0 - pf[0]; aux[ofs+1] = h1 - pf[1]; aux[ofs+2] = h2 - pf[2];
        out[ofs+0] = pf[0]; out[ofs+1] = pf[1]; out[ofs+2] = pf[2];
      } else {
        r0 += pf[0]; r1 += pf[1]; r2 += pf[2];
      }
    }
    __builtin_amdgcn_wave_barrier();
  }
  if (MODE == 2) {
    *(float4*)act[q][0][c] = make_float4(r0, r1, r2, 0.f);
    __syncthreads();
    if (t < 192) {
      const int cc = t / 3, vv = t - cc * 3;
      out[blockIdx.x * 192 + t] =
          act[0][0][cc][vv] + act[1][0][cc][vv] + act[2][0][cc][vv] + act[3][0][cc][vv];
    }
  }
}

// ------- K5: trans = Wt (VNT, 12ch) over xc, lane quads (c = l>>2, v = l&3). -------
__global__ __launch_bounds__(256) void trans_kernel(
    const float* __restrict__ xc,
    const float* __restrict__ Wtf, const float* __restrict__ Wtd,
    float* __restrict__ trans_part) {
  __shared__ float wtf[12][65], wtd[12][65];
  __shared__ float xpt[4][64][4];
  __shared__ float tred[4][12][3];
  const int t = threadIdx.x, q = t >> 6, l = t & 63;
  for (int e = t; e < 768; e += 256) {
    wtf[e >> 6][e & 63] = Wtf[e]; wtd[e >> 6][e & 63] = Wtd[e];
  }
  __syncthreads();
  if (t < 12) {
    float s = 0.f;
    for (int i = 0; i < 64; ++i) s += wtf[t][i];
    s = 1.0f / s;
    for (int i = 0; i < 64; ++i) wtf[t][i] *= s;
  }
  __syncthreads();
  const int cch = l >> 2, v = l & 3;            // cch 0..15, v 0..3
  const bool act = (cch < 12) && (v < 3);
  float ta = 0.f;
  const int pbase = (blockIdx.x * 4 + q) * 8;
  for (int g = 0; g < 8; ++g) {
    const float* xp = xc + (size_t)(pbase + g) * 192 + l * 3;
    xpt[q][l][0] = xp[0]; xpt[q][l][1] = xp[1]; xpt[q][l][2] = xp[2];
    __builtin_amdgcn_wave_barrier();
    float pf = 0.f, pd = 0.f;
    if (act) {
      for (int i = 0; i < 64; ++i) {
        const float a = xpt[q][i][v];
        pf += wtf[cch][i] * a;
        pd += wtd[cch][i] * a;
      }
    }
    float pp = pf * pd, dd = pd * pd;           // inactive lanes contribute 0
    pp += __shfl_xor(pp, 1); pp += __shfl_xor(pp, 2);
    dd += __shfl_xor(dd, 1); dd += __shfl_xor(dd, 2);
    if (pp < 0.f) pf -= (pp / (dd + 1e-6f)) * pd;
    ta += pf;
    __builtin_amdgcn_wave_barrier();
  }
  if (act) { tred[q][cch][v] = ta; }
  __syncthreads();
  if (t < 36) {
    const int cc = t / 3, vv = t - cc * 3;
    trans_part[blockIdx.x * 36 + t] =
        tred[0][cc][vv] + tred[1][cc][vv] + tred[2][cc][vv] + tred[3][cc][vv];
  }
}

// ------- K7: reduce partials, W3 @ mean(h2), concat [rot(116), trans(12)] -------
__global__ __launch_bounds__(384) void finalize_kernel(const float* __restrict__ rot_part,
                                                       const float* __restrict__ trans_part,
                                                       const float* __restrict__ W3,
                                                       float* __restrict__ out) {
  const int b = blockIdx.x;   // 0..3 (128 blocks per batch at grid 512)
  const int t = threadIdx.x;
  __shared__ float hsum[64][3];
  if (t < 192) {
    float s = 0.f;
    for (int blk = 0; blk < 128; ++blk)
      s += rot_part[(b * 128 + blk) * 192 + t];
    hsum[t / 3][t % 3] = s * (1.0f / NPTS);
  } else if (t < 228) {
    const int tt = t - 192;
    float s = 0.f;
    for (int blk = 0; blk < 128; ++blk)
      s += trans_part[(b * 128 + blk) * 36 + tt];
    out[b * 384 + 348 + tt] = s * (1.0f / NPTS);
  }
  __syncthreads();
  if (t < 348) {
    const int ch = t / 3, v = t - ch * 3;
    float s = 0.f;
    for (int i = 0; i < 64; ++i) s += W3[ch * 64 + i] * hsum[i][v];
    out[b * 384 + t] = s;
  }
}

extern "C" void kernel_launch(void* const* d_in, const int* in_sizes, int n_in,
                              void* d_out, int out_size, void* d_ws, size_t ws_size,
                              hipStream_t stream) {
  (void)in_sizes; (void)n_in; (void)out_size; (void)ws_size;
  const float* x     = (const float*)d_in[0];
  const float* Wposf = (const float*)d_in[1];
  const float* Wposd = (const float*)d_in[2];
  const float* Wc1f  = (const float*)d_in[3];
  const float* Wc1d  = (const float*)d_in[4];
  const float* Wc2f  = (const float*)d_in[5];
  const float* Wc2d  = (const float*)d_in[6];
  const float* Wtf   = (const float*)d_in[7];
  const float* Wtd   = (const float*)d_in[8];
  const float* W1f   = (const float*)d_in[9];
  const float* W1d   = (const float*)d_in[10];
  const float* W2f   = (const float*)d_in[11];
  const float* W2d   = (const float*)d_in[12];
  const float* W3    = (const float*)d_in[13];
  float* out = (float*)d_out;

  char* ws = (char*)d_ws;
  int*   knn        = (int*)ws;                          // 1,310,720 B
  float* P          = (float*)(ws + 1310720);            // h -> hc -> y1 (in place)
  float* Q          = (float*)(ws + 13893632);           // x2 -> xc (in place)
  float* trans_part = (float*)(ws + 26476544);           // 512*36*4  = 73,728 B
  float* rot_part   = (float*)(ws + 26550272);           // 512*192*4 = 393,216 B

  knn_kernel<<<BATCH * NPTS, 256, 0, stream>>>(x, knn);
  edge_kernel<<<BATCH * NPTS / 4, 256, 0, stream>>>(x, knn, Wposf, Wposd, P);
  layer_batch<true, 0><<<512, 256, 0, stream>>>(P, Q, nullptr, Wc1f, Wc1d);   // h -> x2
  layer_batch<true, 1><<<512, 256, 0, stream>>>(Q, Q, P, Wc2f, Wc2d);          // x2 -> xc; P := h - xc
  trans_kernel<<<512, 256, 0, stream>>>(Q, Wtf, Wtd, trans_part);              // xc -> trans partials
  layer_batch<false, 0><<<512, 256, 0, stream>>>(P, P, nullptr, W1f, W1d);     // hc -> y1 (in place)
  layer_batch<false, 2><<<512, 256, 0, stream>>>(P, rot_part, nullptr, W2f, W2d); // y1 -> rot partials
  finalize_kernel<<<BATCH, 384, 0, stream>>>(rot_part, trans_part, W3, out);
}